// Round 1
// baseline (1146.087 us; speedup 1.0000x reference)
//
#include <hip/hip_runtime.h>

constexpr int NV  = 100000;
constexpr int NE  = 25000;
constexpr int NNZ = 3200000;
constexpr int IC  = 256;
constexpr int OC  = 128;

// ---------------- GEMM: H = relu(X @ W^T + b) ----------------
// Block: 256 threads computes 32 rows x 128 channels, K-chunks of 64.
// Thread (rg = t>>5, g = t&31) owns rows rg*4+[0..4), channels g+32*[0..4).
__global__ __launch_bounds__(256) void k_gemm(const float* __restrict__ X,
                                              const float* __restrict__ W,
                                              const float* __restrict__ bias,
                                              float* __restrict__ H) {
  __shared__ float Xs[32 * 68];   // stride 68 words: 16B-aligned rows
  __shared__ float Ws[128 * 68];
  const int t = threadIdx.x;
  const int row0 = blockIdx.x * 32;
  const int rg = t >> 5;
  const int g  = t & 31;
  float acc[4][4];
#pragma unroll
  for (int i = 0; i < 4; ++i)
#pragma unroll
    for (int j = 0; j < 4; ++j) acc[i][j] = 0.f;

  for (int kc = 0; kc < IC; kc += 64) {
    __syncthreads();
    // X tile: 32x64 floats = 512 float4
#pragma unroll
    for (int q = 0; q < 2; ++q) {
      int lin = q * 256 + t;
      int r = lin >> 4, m = lin & 15;
      float4 x = *reinterpret_cast<const float4*>(&X[(size_t)(row0 + r) * IC + kc + m * 4]);
      float* d = &Xs[r * 68 + m * 4];
      d[0] = x.x; d[1] = x.y; d[2] = x.z; d[3] = x.w;
    }
    // W tile: 128x64 floats = 2048 float4 (W already [OC][IC] row-major = [c][k])
#pragma unroll
    for (int q = 0; q < 8; ++q) {
      int lin = q * 256 + t;
      int c = lin >> 4, m = lin & 15;
      float4 w = *reinterpret_cast<const float4*>(&W[(size_t)c * IC + kc + m * 4]);
      float* d = &Ws[c * 68 + m * 4];
      d[0] = w.x; d[1] = w.y; d[2] = w.z; d[3] = w.w;
    }
    __syncthreads();
#pragma unroll 2
    for (int kk = 0; kk < 64; kk += 4) {
      float4 xa[4], wb[4];
#pragma unroll
      for (int i = 0; i < 4; ++i)
        xa[i] = *reinterpret_cast<const float4*>(&Xs[(rg * 4 + i) * 68 + kk]);
#pragma unroll
      for (int j = 0; j < 4; ++j)
        wb[j] = *reinterpret_cast<const float4*>(&Ws[(g + 32 * j) * 68 + kk]);
#pragma unroll
      for (int i = 0; i < 4; ++i)
#pragma unroll
        for (int j = 0; j < 4; ++j)
          acc[i][j] += xa[i].x * wb[j].x + xa[i].y * wb[j].y +
                       xa[i].z * wb[j].z + xa[i].w * wb[j].w;
    }
  }
#pragma unroll
  for (int j = 0; j < 4; ++j) {
    int c = g + 32 * j;
    float bv = bias[c];
#pragma unroll
    for (int i = 0; i < 4; ++i) {
      int r = row0 + rg * 4 + i;
      float v = acc[i][j] + bv;
      H[(size_t)r * OC + c] = v > 0.f ? v : 0.f;
    }
  }
}

// ---------------- CSR build ----------------
__global__ void k_hist(const int* __restrict__ v_idx, const int* __restrict__ e_idx,
                       int* __restrict__ v_cnt, int* __restrict__ e_cnt) {
  int i = blockIdx.x * blockDim.x + threadIdx.x;
  int stride = gridDim.x * blockDim.x;
  for (; i < NNZ; i += stride) {
    atomicAdd(&v_cnt[v_idx[i]], 1);
    atomicAdd(&e_cnt[e_idx[i]], 1);
  }
}

// two-kernel exclusive scan (4096 elements per block)
__global__ void k_scan_partial(const int* __restrict__ src, int* __restrict__ part, int n) {
  int b = blockIdx.x, t = threadIdx.x;
  int i0 = b * 4096 + t * 16;
  int s = 0;
#pragma unroll
  for (int q = 0; q < 16; ++q) { int idx = i0 + q; if (idx < n) s += src[idx]; }
  __shared__ int red[256];
  red[t] = s; __syncthreads();
  for (int o = 128; o > 0; o >>= 1) { if (t < o) red[t] += red[t + o]; __syncthreads(); }
  if (t == 0) part[b] = red[0];
}

__global__ void k_scan_final(const int* __restrict__ src, const int* __restrict__ part,
                             int* __restrict__ dst, int n, int total) {
  int b = blockIdx.x, t = threadIdx.x;
  int base = 0;
  for (int i = 0; i < b; ++i) base += part[i];
  int i0 = b * 4096 + t * 16;
  int v[16]; int s = 0;
#pragma unroll
  for (int q = 0; q < 16; ++q) {
    int idx = i0 + q;
    int x = (idx < n) ? src[idx] : 0;
    v[q] = s; s += x;
  }
  __shared__ int ts[256];
  ts[t] = s; __syncthreads();
  for (int o = 1; o < 256; o <<= 1) {
    int val = 0;
    if (t >= o) val = ts[t - o];
    __syncthreads();
    if (t >= o) ts[t] += val;
    __syncthreads();
  }
  int texcl = base + (t > 0 ? ts[t - 1] : 0);
#pragma unroll
  for (int q = 0; q < 16; ++q) {
    int idx = i0 + q;
    if (idx < n) dst[idx] = texcl + v[q];
  }
  if (b == 0 && t == 0) dst[n] = total;
}

__global__ void k_scatter(const int* __restrict__ v_idx, const int* __restrict__ e_idx,
                          const int* __restrict__ v_off, const int* __restrict__ e_off,
                          int* __restrict__ v_fill, int* __restrict__ e_fill,
                          int* __restrict__ vcsr, int* __restrict__ ecsr) {
  int i = blockIdx.x * blockDim.x + threadIdx.x;
  int stride = gridDim.x * blockDim.x;
  for (; i < NNZ; i += stride) {
    int v = v_idx[i], e = e_idx[i];
    int pe = e_off[e] + atomicAdd(&e_fill[e], 1);
    ecsr[pe] = v;
    int pv = v_off[v] + atomicAdd(&v_fill[v], 1);
    vcsr[pv] = e;
  }
}

// ---------------- segment mean (one block per segment, channel per thread) ----------------
template <bool RELU>
__global__ __launch_bounds__(128) void k_seg_mean(const float* __restrict__ src,
                                                  const int* __restrict__ off,
                                                  const int* __restrict__ csr,
                                                  float* __restrict__ dst) {
  int seg = blockIdx.x;
  int t = threadIdx.x;              // channel 0..127
  int s = off[seg], e = off[seg + 1];
  int deg = e - s;
  __shared__ int lst[256];
  float acc = 0.f;
  for (int base = s; base < e; base += 256) {
    int cnt = min(256, e - base);
    __syncthreads();
    for (int j = t; j < cnt; j += 128) lst[j] = csr[base + j];
    __syncthreads();
    int j = 0;
    for (; j + 4 <= cnt; j += 4) {
      float a0 = src[(size_t)lst[j] * OC + t];
      float a1 = src[(size_t)lst[j + 1] * OC + t];
      float a2 = src[(size_t)lst[j + 2] * OC + t];
      float a3 = src[(size_t)lst[j + 3] * OC + t];
      acc += (a0 + a1) + (a2 + a3);
    }
    for (; j < cnt; ++j) acc += src[(size_t)lst[j] * OC + t];
  }
  float r = acc / (float)(deg > 0 ? deg : 1);
  if (RELU) r = r > 0.f ? r : 0.f;
  dst[(size_t)seg * OC + t] = r;
}

// ---------------- launch ----------------
extern "C" void kernel_launch(void* const* d_in, const int* in_sizes, int n_in,
                              void* d_out, int out_size, void* d_ws, size_t ws_size,
                              hipStream_t stream) {
  const float* X    = (const float*)d_in[0];
  const float* W    = (const float*)d_in[1];
  const float* bias = (const float*)d_in[2];
  const int* v_idx  = (const int*)d_in[3];
  const int* e_idx  = (const int*)d_in[4];
  float* out = (float*)d_out;

  char* ws = (char*)d_ws;
  size_t off = 0;
  auto alloc = [&](size_t bytes) -> void* {
    void* p = ws + off;
    off = (off + bytes + 255) & ~(size_t)255;
    return p;
  };
  float* H      = (float*)alloc((size_t)NV * OC * 4);   // 51.2 MB
  float* e_feat = (float*)alloc((size_t)NE * OC * 4);   // 12.8 MB
  int* ecsr     = (int*)alloc((size_t)NNZ * 4);         // 12.8 MB
  int* vcsr     = (int*)alloc((size_t)NNZ * 4);         // 12.8 MB
  int* e_off    = (int*)alloc((size_t)(NE + 1) * 4);
  int* v_off    = (int*)alloc((size_t)(NV + 1) * 4);
  char* zbase   = ws + off;                             // start of zeroed region
  int* e_cnt    = (int*)alloc((size_t)NE * 4);
  int* v_cnt    = (int*)alloc((size_t)NV * 4);
  int* e_fill   = (int*)alloc((size_t)NE * 4);
  int* v_fill   = (int*)alloc((size_t)NV * 4);
  size_t zbytes = (size_t)((ws + off) - zbase);
  int* e_part   = (int*)alloc(64 * 4);
  int* v_part   = (int*)alloc(64 * 4);

  hipMemsetAsync(zbase, 0, zbytes, stream);

  k_hist<<<2048, 256, 0, stream>>>(v_idx, e_idx, v_cnt, e_cnt);

  int nbE = (NE + 4095) / 4096;   // 7
  int nbV = (NV + 4095) / 4096;   // 25
  k_scan_partial<<<nbE, 256, 0, stream>>>(e_cnt, e_part, NE);
  k_scan_partial<<<nbV, 256, 0, stream>>>(v_cnt, v_part, NV);
  k_scan_final<<<nbE, 256, 0, stream>>>(e_cnt, e_part, e_off, NE, NNZ);
  k_scan_final<<<nbV, 256, 0, stream>>>(v_cnt, v_part, v_off, NV, NNZ);

  k_scatter<<<2048, 256, 0, stream>>>(v_idx, e_idx, v_off, e_off, v_fill, e_fill, vcsr, ecsr);

  k_gemm<<<NV / 32, 256, 0, stream>>>(X, W, bias, H);

  k_seg_mean<false><<<NE, 128, 0, stream>>>(H, e_off, ecsr, e_feat);
  k_seg_mean<true><<<NV, 128, 0, stream>>>(e_feat, v_off, vcsr, out);
}